// Round 2
// baseline (7134.268 us; speedup 1.0000x reference)
//
#include <hip/hip_runtime.h>
#include <hip/hip_cooperative_groups.h>

namespace cg = cooperative_groups;

typedef float f32x4 __attribute__((ext_vector_type(4)));

#define NXg   512
#define NYg   512
#define NTt   400
#define DIMg  520
#define DTc   0.001f
#define Hc    10.0f
#define KSTEP 4
#define NCHUNK (NTt / KSTEP)   // 100

#define C0f (-205.0f/72.0f)
#define C1f (8.0f/5.0f)
#define C2f (-1.0f/5.0f)
#define C3f (8.0f/315.0f)
#define C4f (-1.0f/560.0f)

// Persistent cooperative kernel. 256 blocks (16x16), 256 threads each.
// Each block owns a 32x32 interior tile, loads a 64x64 tile (16-halo) into
// LDS, runs 4 substeps with erosion, writes owned region of the last two
// time levels to double-buffered global fields, grid.sync(), repeat x100.
__launch_bounds__(256)
__global__ void time2d_coop(const float* __restrict__ vel,
                            const float* __restrict__ w,
                            const int* __restrict__ sxp,
                            const int* __restrict__ syp,
                            const int* __restrict__ ryp,
                            float* __restrict__ out,
                            float* __restrict__ ws)
{
    cg::grid_group gg = cg::this_grid();

    float* bufP[2] = { ws,                ws + 2*DIMg*DIMg };
    float* bufC[2] = { ws + DIMg*DIMg,    ws + 3*DIMg*DIMg };

    const int tid  = threadIdx.x;
    const int bx   = blockIdx.x, by = blockIdx.y;
    const int flat = (by*16 + bx)*256 + tid;

    // Zero all 4 field buffers (ws is poisoned 0xAA; pad ring must be 0).
    {
        f32x4* q = (f32x4*)ws;
        const int nq = 4*DIMg*DIMg/4;   // 270400 quads
        for (int i = flat; i < nq; i += 65536) q[i] = (f32x4)0.0f;
    }

    const int sx = *sxp, sy = *syp, ry = *ryp;
    const int iy = sy + 4, ix = sx + 4, iyr = ry + 4;
    const float va  = vel[sx*NYg + sy] * DTc;
    const float amp = va * va;

    const int xc = tid & 15, yg = tid >> 4;
    const int x4 = xc*4, rb = yg*4;
    const bool active = (yg < 14);            // computed rows [4,60) = 14 groups of 4
    const int lx0 = bx*32 - 12, ly0 = by*32 - 12;
    const int gx0 = lx0 + x4;
    const bool ownedCol = (x4 >= 16 && x4 < 48);

    // Per-cell scale with mask folded in (0 outside interior), source pos,
    // receiver-row flags. All fixed for the whole run.
    f32x4 scq[4];
    int srcI = -1, srcJ = 0;
    bool rec[4]; int gyv[4];
    #pragma unroll
    for (int i = 0; i < 4; ++i) {
        const int gy = ly0 + 4 + rb + i;
        gyv[i] = gy;
        #pragma unroll
        for (int j = 0; j < 4; ++j) {
            const int gx = gx0 + j;
            float s = 0.0f;
            if (gy >= 4 && gy < 516 && gx >= 4 && gx < 516) {
                // scale[gy][gx] = (vel[gx-4][gy-4]*DT)^2 / H^2  (transposed pad)
                const float vv = vel[(gx-4)*NYg + (gy-4)] * DTc;
                s = vv*vv/(Hc*Hc);
            }
            scq[i][j] = s;
            if (gy == iy && gx == ix) { srcI = i; srcJ = j; }
        }
        rec[i] = (gy == iyr) && ownedCol && ((unsigned)(rb + i - 12) < 32u);
    }

    __shared__ float lds[2][64*64];   // two cur-field ping-pong buffers, 32 KB

    gg.sync();   // zeroed buffers visible everywhere

    f32x4 prevq[4], valq[4];
    #pragma unroll 1
    for (int c = 0; c < NCHUNK; ++c) {
        const float* __restrict__ Ps = bufP[c & 1];
        const float* __restrict__ Cs = bufC[c & 1];
        float* __restrict__ Pd = bufP[(c & 1) ^ 1];
        float* __restrict__ Cd = bufC[(c & 1) ^ 1];

        // Load cur tile (64x64) into LDS[0], coalesced f32x4.
        #pragma unroll
        for (int ii = 0; ii < 4; ++ii) {
            const int pos = (tid + 256*ii) * 4;       // 1024 quads
            const int ty = pos >> 6, tx = pos & 63;
            const int gy = ly0 + ty, gx = lx0 + tx;
            f32x4 v = (f32x4)0.0f;
            if ((unsigned)gy < 520u && (unsigned)gx < 520u)
                v = *(const f32x4*)&Cs[gy*DIMg + gx];
            *(f32x4*)&lds[0][pos] = v;
        }
        // Load prev level into registers (pointwise use only).
        #pragma unroll
        for (int i = 0; i < 4; ++i) {
            const int gy = gyv[i];
            f32x4 v = (f32x4)0.0f;
            if ((unsigned)gy < 520u && (unsigned)gx0 < 520u)
                v = *(const f32x4*)&Ps[gy*DIMg + gx0];
            prevq[i] = v;
        }
        __syncthreads();

        int p = 0;
        #pragma unroll
        for (int k = 0; k < KSTEP; ++k) {
            const int t = c*KSTEP + k;
            const float inj = (srcI >= 0) ? w[t]*amp : 0.0f;
            const float* cur = lds[p];
            float* nxt = lds[p^1];
            if (active) {
                // vertical window: rows rb..rb+11 at columns [x4, x4+4)
                f32x4 win[12];
                #pragma unroll
                for (int m = 0; m < 12; ++m)
                    win[m] = *(const f32x4*)&cur[(rb+m)*64 + x4];
                #pragma unroll
                for (int i = 0; i < 4; ++i) {
                    const int y = 4 + rb + i;
                    const f32x4 lq = *(const f32x4*)&cur[y*64 + x4 - 4];
                    const f32x4 rq = *(const f32x4*)&cur[y*64 + x4 + 4];
                    float h[12];
                    #pragma unroll
                    for (int j = 0; j < 4; ++j) {
                        h[j] = lq[j]; h[4+j] = win[4+i][j]; h[8+j] = rq[j];
                    }
                    f32x4 nv;
                    #pragma unroll
                    for (int j = 0; j < 4; ++j) {
                        const float ctr = h[4+j];
                        const float lap = 2.0f*C0f*ctr
                          + C1f*(win[3+i][j] + win[5+i][j] + h[3+j] + h[5+j])
                          + C2f*(win[2+i][j] + win[6+i][j] + h[2+j] + h[6+j])
                          + C3f*(win[1+i][j] + win[7+i][j] + h[1+j] + h[7+j])
                          + C4f*(win[0+i][j] + win[8+i][j] + h[0+j] + h[8+j]);
                        float nvj = 2.0f*ctr - prevq[i][j] + scq[i][j]*lap;
                        if (srcI == i && srcJ == j) nvj += inj;   // source add (post-mask)
                        nv[j] = nvj;
                        prevq[i][j] = ctr;                         // u(t) becomes prev
                    }
                    *(f32x4*)&nxt[y*64 + x4] = nv;
                    valq[i] = nv;
                    if (rec[i])   // receiver row, owned (always-valid) cells, post-source
                        *(f32x4*)&out[(size_t)t*NXg + (gx0 - 4)] = nv;
                }
            }
            __syncthreads();
            p ^= 1;
        }

        // Write back owned 32x32 region of last two levels (in registers).
        if (ownedCol) {
            #pragma unroll
            for (int i = 0; i < 4; ++i) {
                if ((unsigned)(rb + i - 12) < 32u) {
                    const size_t g = (size_t)gyv[i]*DIMg + gx0;
                    *(f32x4*)&Pd[g] = prevq[i];   // u(T+3)
                    *(f32x4*)&Cd[g] = valq[i];    // u(T+4)
                }
            }
        }
        __threadfence();
        gg.sync();
    }
}

extern "C" void kernel_launch(void* const* d_in, const int* in_sizes, int n_in,
                              void* d_out, int out_size, void* d_ws, size_t ws_size,
                              hipStream_t stream) {
    const float* vel = (const float*)d_in[0];
    const float* w   = (const float*)d_in[1];
    const int*   sx  = (const int*)d_in[2];
    const int*   sy  = (const int*)d_in[3];
    const int*   ry  = (const int*)d_in[4];
    float* out = (float*)d_out;
    float* ws  = (float*)d_ws;   // needs 4*520*520*4 B = 4.33 MB

    void* args[] = { (void*)&vel, (void*)&w, (void*)&sx, (void*)&sy, (void*)&ry,
                     (void*)&out, (void*)&ws };
    hipLaunchCooperativeKernel((void*)time2d_coop, dim3(16,16), dim3(256),
                               args, 0, stream);
}

// Round 3
// 932.494 us; speedup vs baseline: 7.6507x; 7.6507x over previous
//
#include <hip/hip_runtime.h>

typedef float f32x4 __attribute__((ext_vector_type(4)));

#define NXg   512
#define NYg   512
#define NTt   400
#define DIMg  520
#define DTc   0.001f
#define Hc    10.0f
#define KSTEP 4
#define NCHUNK (NTt / KSTEP)   // 100

#define C0f (-205.0f/72.0f)
#define C1f (8.0f/5.0f)
#define C2f (-1.0f/5.0f)
#define C3f (8.0f/315.0f)
#define C4f (-1.0f/560.0f)

// One-time per call: build scale[] (mask folded in: 0 on the 4-wide pad ring)
// and zero the 4 field buffers. ws is poisoned 0xAA and never re-poisoned.
__global__ void time2d_init(const float* __restrict__ vel,
                            float* __restrict__ scale,
                            float* __restrict__ fields /* 4*DIMg*DIMg */) {
    int idx = blockIdx.x * blockDim.x + threadIdx.x;
    if (idx < DIMg * DIMg) {
        int y = idx / DIMg;
        int x = idx - y * DIMg;
        float s = 0.0f;
        if (y >= 4 && y < 516 && x >= 4 && x < 516) {
            // scale[y][x] = (vel[x-4][y-4]*DT)^2 / H^2   (transposed pad)
            float v = vel[(x - 4) * NYg + (y - 4)] * DTc;
            s = v * v / (Hc * Hc);
        }
        scale[idx] = s;
    }
    for (int i = idx; i < 4 * DIMg * DIMg; i += gridDim.x * blockDim.x)
        fields[i] = 0.0f;
}

// One chunk = 4 time steps. 256 blocks (16x16), 256 threads. Each block owns
// a 32x32 interior tile, loads a 64x64 tile (12-halo + computed margin) into
// LDS, runs 4 substeps with erosion (verified structure from round 2), writes
// the owned region of the last two time levels to the destination buffers.
// No inter-block sync: redundant halo compute makes blocks independent.
__launch_bounds__(256)
__global__ void time2d_chunk(const float* __restrict__ Ps,
                             const float* __restrict__ Cs,
                             float* __restrict__ Pd,
                             float* __restrict__ Cd,
                             const float* __restrict__ scale,
                             const float* __restrict__ w,
                             const float* __restrict__ vel,
                             const int* __restrict__ sxp,
                             const int* __restrict__ syp,
                             const int* __restrict__ ryp,
                             float* __restrict__ out,
                             int t0)
{
    const int tid = threadIdx.x;
    const int bx  = blockIdx.x, by = blockIdx.y;

    const int sx = *sxp, sy = *syp, ry = *ryp;
    const int iy = sy + 4, ix = sx + 4, iyr = ry + 4;
    const float va  = vel[sx * NYg + sy] * DTc;
    const float amp = va * va;

    const int xc = tid & 15, yg = tid >> 4;
    const int x4 = xc * 4, rb = yg * 4;
    const bool active = (yg < 14);           // computed rows local [4,60)
    const int lx0 = bx * 32 - 12, ly0 = by * 32 - 12;
    const int gx0 = lx0 + x4;
    const bool ownedCol = (x4 >= 16 && x4 < 48);

    // Per-thread constants: scale quads, source position, receiver flags.
    f32x4 scq[4];
    int srcI = -1, srcJ = 0;
    bool rec[4]; int gyv[4];
    #pragma unroll
    for (int i = 0; i < 4; ++i) {
        const int gy = ly0 + 4 + rb + i;
        gyv[i] = gy;
        f32x4 s = (f32x4)0.0f;
        if ((unsigned)gy < 520u && (unsigned)gx0 < 517u)
            s = *(const f32x4*)&scale[gy * DIMg + gx0];
        scq[i] = s;
        #pragma unroll
        for (int j = 0; j < 4; ++j)
            if (gy == iy && gx0 + j == ix) { srcI = i; srcJ = j; }
        rec[i] = (gy == iyr) && ownedCol && ((unsigned)(rb + i - 12) < 32u);
    }

    __shared__ float lds[2][64 * 64];

    // Load cur tile (64x64) into LDS[0], coalesced f32x4.
    #pragma unroll
    for (int ii = 0; ii < 4; ++ii) {
        const int pos = (tid + 256 * ii) * 4;
        const int ty = pos >> 6, tx = pos & 63;
        const int gy = ly0 + ty, gx = lx0 + tx;
        f32x4 v = (f32x4)0.0f;
        if ((unsigned)gy < 520u && (unsigned)gx < 520u)
            v = *(const f32x4*)&Cs[gy * DIMg + gx];
        *(f32x4*)&lds[0][pos] = v;
    }
    // Prev level into registers (pointwise use only).
    f32x4 prevq[4], valq[4];
    #pragma unroll
    for (int i = 0; i < 4; ++i) {
        const int gy = gyv[i];
        f32x4 v = (f32x4)0.0f;
        if ((unsigned)gy < 520u && (unsigned)gx0 < 520u)
            v = *(const f32x4*)&Ps[gy * DIMg + gx0];
        prevq[i] = v;
    }
    __syncthreads();

    int p = 0;
    #pragma unroll
    for (int k = 0; k < KSTEP; ++k) {
        const int t = t0 + k;
        const float inj = (srcI >= 0) ? w[t] * amp : 0.0f;
        const float* cur = lds[p];
        float* nxt = lds[p ^ 1];
        if (active) {
            f32x4 win[12];
            #pragma unroll
            for (int m = 0; m < 12; ++m)
                win[m] = *(const f32x4*)&cur[(rb + m) * 64 + x4];
            #pragma unroll
            for (int i = 0; i < 4; ++i) {
                const int y = 4 + rb + i;
                const f32x4 lq = *(const f32x4*)&cur[y * 64 + x4 - 4];
                const f32x4 rq = *(const f32x4*)&cur[y * 64 + x4 + 4];
                float h[12];
                #pragma unroll
                for (int j = 0; j < 4; ++j) {
                    h[j] = lq[j]; h[4 + j] = win[4 + i][j]; h[8 + j] = rq[j];
                }
                f32x4 nv;
                #pragma unroll
                for (int j = 0; j < 4; ++j) {
                    const float ctr = h[4 + j];
                    const float lap = 2.0f * C0f * ctr
                      + C1f * (win[3 + i][j] + win[5 + i][j] + h[3 + j] + h[5 + j])
                      + C2f * (win[2 + i][j] + win[6 + i][j] + h[2 + j] + h[6 + j])
                      + C3f * (win[1 + i][j] + win[7 + i][j] + h[1 + j] + h[7 + j])
                      + C4f * (win[0 + i][j] + win[8 + i][j] + h[0 + j] + h[8 + j]);
                    float nvj = 2.0f * ctr - prevq[i][j] + scq[i][j] * lap;
                    if (srcI == i && srcJ == j) nvj += inj;
                    nv[j] = nvj;
                    prevq[i][j] = ctr;
                }
                *(f32x4*)&nxt[y * 64 + x4] = nv;
                valq[i] = nv;
                if (rec[i])
                    *(f32x4*)&out[(size_t)t * NXg + (gx0 - 4)] = nv;
            }
        }
        __syncthreads();
        p ^= 1;
    }

    // Write back owned 32x32 region of the last two time levels.
    if (ownedCol) {
        #pragma unroll
        for (int i = 0; i < 4; ++i) {
            if ((unsigned)(rb + i - 12) < 32u) {
                const size_t g = (size_t)gyv[i] * DIMg + gx0;
                *(f32x4*)&Pd[g] = prevq[i];   // u(t0+3)
                *(f32x4*)&Cd[g] = valq[i];    // u(t0+4)
            }
        }
    }
}

extern "C" void kernel_launch(void* const* d_in, const int* in_sizes, int n_in,
                              void* d_out, int out_size, void* d_ws, size_t ws_size,
                              hipStream_t stream) {
    const float* vel = (const float*)d_in[0];
    const float* w   = (const float*)d_in[1];
    const int*   sx  = (const int*)d_in[2];
    const int*   sy  = (const int*)d_in[3];
    const int*   ry  = (const int*)d_in[4];
    float* out = (float*)d_out;

    float* ws    = (float*)d_ws;           // needs 5*520*520*4 B = 5.4 MB
    float* scale = ws;
    float* fld   = ws + DIMg * DIMg;
    float* P[2]  = { fld,                fld + 2 * DIMg * DIMg };
    float* C[2]  = { fld + DIMg * DIMg,  fld + 3 * DIMg * DIMg };

    time2d_init<<<(DIMg * DIMg + 255) / 256, 256, 0, stream>>>(vel, scale, fld);

    dim3 grid(16, 16);
    for (int c = 0; c < NCHUNK; ++c) {
        const int s = c & 1, d = s ^ 1;
        time2d_chunk<<<grid, 256, 0, stream>>>(P[s], C[s], P[d], C[d],
                                               scale, w, vel, sx, sy, ry,
                                               out, c * KSTEP);
    }
}

// Round 4
// 880.888 us; speedup vs baseline: 8.0989x; 1.0586x over previous
//
#include <hip/hip_runtime.h>

typedef float f32x4 __attribute__((ext_vector_type(4)));

#define NXg   512
#define NYg   512
#define NTt   400
#define DIMg  520
#define DTc   0.001f
#define Hc    10.0f

#define TILE   80          // 80x80 tile, own 32x32, halo 24 (K<=6)
#define TSTR   84          // padded LDS row stride (floats)
#define NQROW  20          // quads per tile row
#define NQUADS (TILE*NQROW)  // 1600

#define C0f (-205.0f/72.0f)
#define C1f (8.0f/5.0f)
#define C2f (-1.0f/5.0f)
#define C3f (8.0f/315.0f)
#define C4f (-1.0f/560.0f)

// One-time per call: scale[] (mask folded: 0 on pad ring), zero fields,
// params: [0..2]=srcY,srcX,recY (ints), [4+t]=w[t]*amp.
__global__ void time2d_init(const float* __restrict__ vel,
                            const float* __restrict__ w,
                            const int* __restrict__ sxp,
                            const int* __restrict__ syp,
                            const int* __restrict__ ryp,
                            float* __restrict__ scale,
                            float* __restrict__ fields,
                            float* __restrict__ params) {
    int idx = blockIdx.x * blockDim.x + threadIdx.x;
    if (idx < DIMg * DIMg) {
        int y = idx / DIMg;
        int x = idx - y * DIMg;
        float s = 0.0f;
        if (y >= 4 && y < 516 && x >= 4 && x < 516) {
            // scale[y][x] = (vel[x-4][y-4]*DT)^2 / H^2   (transposed pad)
            float v = vel[(x - 4) * NYg + (y - 4)] * DTc;
            s = v * v / (Hc * Hc);
        }
        scale[idx] = s;
    }
    for (int i = idx; i < 4 * DIMg * DIMg; i += gridDim.x * blockDim.x)
        fields[i] = 0.0f;
    if (idx < NTt) {
        const int sx = *sxp, sy = *syp;
        const float va = vel[sx * NYg + sy] * DTc;
        params[4 + idx] = w[idx] * (va * va);
    }
    if (idx == 0) {
        int* pi = (int*)params;
        pi[0] = *syp + 4;   // srcY
        pi[1] = *sxp + 4;   // srcX
        pi[2] = *ryp + 4;   // recY
    }
}

// One chunk = K time steps (K<=6). 256 blocks, 512 threads. Block owns a
// 32x32 interior tile, stages an 80x80 tile in double-buffered LDS, runs K
// substeps with erosion (validated structure), writes back the owned region
// of the last two time levels. Blocks independent within a launch.
template<int K>
__launch_bounds__(512)
__global__ void time2d_chunk(const float* __restrict__ Ps,
                             const float* __restrict__ Cs,
                             float* __restrict__ Pd,
                             float* __restrict__ Cd,
                             const float* __restrict__ scale,
                             const float* __restrict__ params,
                             float* __restrict__ out,
                             int t0)
{
    const int tid = threadIdx.x;
    const int bx = blockIdx.x, by = blockIdx.y;
    const int lx0 = bx * 32 - 20, ly0 = by * 32 - 20;   // tile origin (global)

    const int* pi = (const int*)params;
    const int srcY = pi[0], srcX = pi[1], recY = pi[2];

    __shared__ float lds[2][TILE * TSTR];

    // Stage cur tile into LDS[0] (f32x4 quads; OOB -> 0 == pad semantics).
    #pragma unroll
    for (int ii = 0; ii < 4; ++ii) {
        const int pos = tid + 512 * ii;
        if (pos < NQUADS) {
            const int ty = pos / NQROW, txq = pos - ty * NQROW;
            const int gy = ly0 + ty, gx = lx0 + txq * 4;
            f32x4 v = (f32x4)0.0f;
            if ((unsigned)gy < 520u && (unsigned)gx < 517u)
                v = *(const f32x4*)&Cs[gy * DIMg + gx];
            *(f32x4*)&lds[0][ty * TSTR + txq * 4] = v;
        }
    }

    // Compute-thread mapping: 360 active threads, 4x4 cells each,
    // covering local rows [4,76) x all 20 quad-cols.
    const int ct = tid;
    const bool active = (ct < 360);
    const int xc = ct % NQROW, yg = ct / NQROW;
    const int x4 = xc * 4;
    const int rb = 4 + yg * 4;                 // first computed local row
    const int gx0 = lx0 + x4;
    const bool ownedCol = (xc >= 6 && xc < 14);
    const bool ownedRow = ((unsigned)(rb - 24) < 32u);

    f32x4 scq[4], prevq[4], valq[4];
    int srcI = -1, srcJ = 0;
    bool rec[4];
    #pragma unroll
    for (int i = 0; i < 4; ++i) {
        const int gy = ly0 + rb + i;
        f32x4 s = (f32x4)0.0f, pv = (f32x4)0.0f;
        if (active && (unsigned)gy < 520u && (unsigned)gx0 < 517u) {
            s  = *(const f32x4*)&scale[gy * DIMg + gx0];
            pv = *(const f32x4*)&Ps[gy * DIMg + gx0];
        }
        scq[i] = s; prevq[i] = pv;
        #pragma unroll
        for (int j = 0; j < 4; ++j)
            if (gy == srcY && gx0 + j == srcX) { srcI = i; srcJ = j; }
        rec[i] = active && ownedCol && ownedRow && (gy == recY);
    }

    float injs[K];
    #pragma unroll
    for (int k = 0; k < K; ++k)
        injs[k] = (srcI >= 0) ? params[4 + t0 + k] : 0.0f;

    __syncthreads();

    int p = 0;
    #pragma unroll
    for (int k = 0; k < K; ++k) {
        const float* cur = lds[p];
        float* nxt = lds[p ^ 1];
        if (active) {
            f32x4 win[12];
            #pragma unroll
            for (int m = 0; m < 12; ++m)
                win[m] = *(const f32x4*)&cur[(rb - 4 + m) * TSTR + x4];
            #pragma unroll
            for (int i = 0; i < 4; ++i) {
                const int y = rb + i;
                const f32x4 lq = *(const f32x4*)&cur[y * TSTR + x4 - 4];
                const f32x4 rq = *(const f32x4*)&cur[y * TSTR + x4 + 4];
                float h[12];
                #pragma unroll
                for (int j = 0; j < 4; ++j) {
                    h[j] = lq[j]; h[4 + j] = win[4 + i][j]; h[8 + j] = rq[j];
                }
                f32x4 nv;
                #pragma unroll
                for (int j = 0; j < 4; ++j) {
                    const float ctr = h[4 + j];
                    const float lap = 2.0f * C0f * ctr
                      + C1f * (win[3 + i][j] + win[5 + i][j] + h[3 + j] + h[5 + j])
                      + C2f * (win[2 + i][j] + win[6 + i][j] + h[2 + j] + h[6 + j])
                      + C3f * (win[1 + i][j] + win[7 + i][j] + h[1 + j] + h[7 + j])
                      + C4f * (win[0 + i][j] + win[8 + i][j] + h[0 + j] + h[8 + j]);
                    float nvj = 2.0f * ctr - prevq[i][j] + scq[i][j] * lap;
                    if (srcI == i && srcJ == j) nvj += injs[k];
                    nv[j] = nvj;
                    prevq[i][j] = ctr;
                }
                *(f32x4*)&nxt[y * TSTR + x4] = nv;
                valq[i] = nv;
                if (rec[i])
                    *(f32x4*)&out[(size_t)(t0 + k) * NXg + (gx0 - 4)] = nv;
            }
        }
        __syncthreads();
        p ^= 1;
    }

    // Write back owned 32x32 region of the last two time levels.
    if (active && ownedCol && ownedRow) {
        #pragma unroll
        for (int i = 0; i < 4; ++i) {
            const size_t g = (size_t)(ly0 + rb + i) * DIMg + gx0;
            *(f32x4*)&Pd[g] = prevq[i];   // u(t0+K-1)
            *(f32x4*)&Cd[g] = valq[i];    // u(t0+K)
        }
    }
}

extern "C" void kernel_launch(void* const* d_in, const int* in_sizes, int n_in,
                              void* d_out, int out_size, void* d_ws, size_t ws_size,
                              hipStream_t stream) {
    const float* vel = (const float*)d_in[0];
    const float* w   = (const float*)d_in[1];
    const int*   sx  = (const int*)d_in[2];
    const int*   sy  = (const int*)d_in[3];
    const int*   ry  = (const int*)d_in[4];
    float* out = (float*)d_out;

    float* ws     = (float*)d_ws;     // needs ~5.41 MB
    float* scale  = ws;
    float* params = ws + DIMg * DIMg;
    float* fld    = params + 512;
    float* P[2]   = { fld,               fld + 2 * DIMg * DIMg };
    float* C[2]   = { fld + DIMg * DIMg, fld + 3 * DIMg * DIMg };

    time2d_init<<<(DIMg * DIMg + 255) / 256, 256, 0, stream>>>(
        vel, w, sx, sy, ry, scale, fld, params);

    dim3 grid(16, 16);
    // 66 chunks of K=6 (t=0..395) + 1 chunk of K=4 (t=396..399)
    for (int c = 0; c < 66; ++c) {
        const int s = c & 1, d = s ^ 1;
        time2d_chunk<6><<<grid, 512, 0, stream>>>(P[s], C[s], P[d], C[d],
                                                  scale, params, out, c * 6);
    }
    {
        const int c = 66, s = c & 1, d = s ^ 1;
        time2d_chunk<4><<<grid, 512, 0, stream>>>(P[s], C[s], P[d], C[d],
                                                  scale, params, out, 396);
    }
}

// Round 5
// 871.834 us; speedup vs baseline: 8.1831x; 1.0104x over previous
//
#include <hip/hip_runtime.h>

typedef float f32x4 __attribute__((ext_vector_type(4)));

#define NXg   512
#define NYg   512
#define NTt   400
#define DIMg  520
#define DTc   0.001f
#define Hc    10.0f
#define KSTEP 4
#define NCHUNK 100

#define TILE_W 64          // x extent of staged tile (own 32 + 2*16 halo)
#define TILE_H 48          // y extent of staged tile (own 16 + 2*16 halo)
#define TSTR   68          // padded LDS row stride (floats)
#define NQROW  16          // f32x4 quads per tile row
#define NQUADS (TILE_H * NQROW)   // 768

#define C0f (-205.0f/72.0f)
#define C1f (8.0f/5.0f)
#define C2f (-1.0f/5.0f)
#define C3f (8.0f/315.0f)
#define C4f (-1.0f/560.0f)

// One-time per call: scale[] (mask folded in: 0 on pad ring), zero fields,
// params: ints [0..2]=srcY,srcX,recY ; floats [4+t]=w[t]*amp.
__global__ void time2d_init(const float* __restrict__ vel,
                            const float* __restrict__ w,
                            const int* __restrict__ sxp,
                            const int* __restrict__ syp,
                            const int* __restrict__ ryp,
                            float* __restrict__ scale,
                            float* __restrict__ fields,
                            float* __restrict__ params) {
    int idx = blockIdx.x * blockDim.x + threadIdx.x;
    if (idx < DIMg * DIMg) {
        int y = idx / DIMg;
        int x = idx - y * DIMg;
        float s = 0.0f;
        if (y >= 4 && y < 516 && x >= 4 && x < 516) {
            // scale[y][x] = (vel[x-4][y-4]*DT)^2 / H^2   (transposed pad)
            float v = vel[(x - 4) * NYg + (y - 4)] * DTc;
            s = v * v / (Hc * Hc);
        }
        scale[idx] = s;
    }
    for (int i = idx; i < 4 * DIMg * DIMg; i += gridDim.x * blockDim.x)
        fields[i] = 0.0f;
    if (idx < NTt) {
        const int sx = *sxp, sy = *syp;
        const float va = vel[sx * NYg + sy] * DTc;
        params[4 + idx] = w[idx] * (va * va);
    }
    if (idx == 0) {
        int* pi = (int*)params;
        pi[0] = *syp + 4;   // srcY
        pi[1] = *sxp + 4;   // srcX
        pi[2] = *ryp + 4;   // recY
    }
}

// One chunk = K=4 steps. 512 blocks (16x32) = 2 blocks/CU, 320 threads each,
// ALL active in compute (5 full waves). Block owns a 32x16 interior tile,
// stages 64x48 into double-buffered LDS, runs 4 substeps with erosion
// (valid region after 4 substeps = owned region exactly), writes back the
// owned region of the last two time levels. Blocks independent in a launch.
template<int K>
__launch_bounds__(320, 3)
__global__ void time2d_chunk(const float* __restrict__ Ps,
                             const float* __restrict__ Cs,
                             float* __restrict__ Pd,
                             float* __restrict__ Cd,
                             const float* __restrict__ scale,
                             const float* __restrict__ params,
                             float* __restrict__ out,
                             int t0)
{
    const int tid = threadIdx.x;
    const int bx = blockIdx.x, by = blockIdx.y;
    const int lx0 = bx * 32 - 12, ly0 = by * 16 - 12;   // tile origin (global)

    const int* pi = (const int*)params;
    const int srcY = pi[0], srcX = pi[1], recY = pi[2];

    __shared__ float lds[2][TILE_H * TSTR];

    // Stage cur tile (64x48) into LDS[0]; OOB -> 0 (pad semantics).
    #pragma unroll
    for (int ii = 0; ii < 3; ++ii) {
        const int pos = tid + 320 * ii;
        if (pos < NQUADS) {
            const int ty = pos >> 4, txq = pos & 15;
            const int gy = ly0 + ty, gx = lx0 + txq * 4;
            f32x4 v = (f32x4)0.0f;
            if ((unsigned)gy < 520u && (unsigned)gx < 517u)
                v = *(const f32x4*)&Cs[gy * DIMg + gx];
            *(f32x4*)&lds[0][ty * TSTR + txq * 4] = v;
        }
    }

    // Compute mapping: 4 wide x 2 tall cells/thread, rows [4,44) x 16 qcols.
    const int xc = tid & 15, pr = tid >> 4;   // pr 0..19
    const int x4 = xc * 4;
    const int rb = 4 + pr * 2;                // computed rows rb, rb+1
    const int gx0 = lx0 + x4;
    const bool ownedCol = (xc >= 4 && xc < 12);   // own local x [16,48)

    f32x4 scq[2], prevq[2], valq[2];
    int srcI = -1, srcJ = 0;
    bool rec[2], ownRow[2];
    int gyv[2];
    #pragma unroll
    for (int i = 0; i < 2; ++i) {
        const int gy = ly0 + rb + i;
        gyv[i] = gy;
        f32x4 s = (f32x4)0.0f, pv = (f32x4)0.0f;
        if ((unsigned)gy < 520u && (unsigned)gx0 < 517u) {
            s  = *(const f32x4*)&scale[gy * DIMg + gx0];
            pv = *(const f32x4*)&Ps[gy * DIMg + gx0];
        }
        scq[i] = s; prevq[i] = pv;
        #pragma unroll
        for (int j = 0; j < 4; ++j)
            if (gy == srcY && gx0 + j == srcX) { srcI = i; srcJ = j; }
        ownRow[i] = ((unsigned)(rb + i - 16) < 16u);  // own local y [16,32)
        rec[i] = ownedCol && ownRow[i] && (gy == recY);
    }

    float injs[K];
    #pragma unroll
    for (int k = 0; k < K; ++k)
        injs[k] = (srcI >= 0) ? params[4 + t0 + k] : 0.0f;

    __syncthreads();

    int p = 0;
    #pragma unroll
    for (int k = 0; k < K; ++k) {
        const float* cur = lds[p];
        float* nxt = lds[p ^ 1];
        // center column quads, rows rb-4 .. rb+5
        f32x4 win[10];
        #pragma unroll
        for (int m = 0; m < 10; ++m)
            win[m] = *(const f32x4*)&cur[(rb - 4 + m) * TSTR + x4];
        #pragma unroll
        for (int i = 0; i < 2; ++i) {
            const int y = rb + i;
            const f32x4 lq = *(const f32x4*)&cur[y * TSTR + x4 - 4];
            const f32x4 rq = *(const f32x4*)&cur[y * TSTR + x4 + 4];
            float h[12];
            #pragma unroll
            for (int j = 0; j < 4; ++j) {
                h[j] = lq[j]; h[4 + j] = win[4 + i][j]; h[8 + j] = rq[j];
            }
            f32x4 nv;
            #pragma unroll
            for (int j = 0; j < 4; ++j) {
                const float ctr = h[4 + j];
                const float lap = 2.0f * C0f * ctr
                  + C1f * (win[3 + i][j] + win[5 + i][j] + h[3 + j] + h[5 + j])
                  + C2f * (win[2 + i][j] + win[6 + i][j] + h[2 + j] + h[6 + j])
                  + C3f * (win[1 + i][j] + win[7 + i][j] + h[1 + j] + h[7 + j])
                  + C4f * (win[0 + i][j] + win[8 + i][j] + h[0 + j] + h[8 + j]);
                float nvj = 2.0f * ctr - prevq[i][j] + scq[i][j] * lap;
                if (srcI == i && srcJ == j) nvj += injs[k];
                nv[j] = nvj;
                prevq[i][j] = ctr;
            }
            *(f32x4*)&nxt[y * TSTR + x4] = nv;
            valq[i] = nv;
            if (rec[i])
                *(f32x4*)&out[(size_t)(t0 + k) * NXg + (gx0 - 4)] = nv;
        }
        if (k < K - 1) __syncthreads();
        p ^= 1;
    }

    // Write back owned 32x16 region of the last two time levels.
    if (ownedCol) {
        #pragma unroll
        for (int i = 0; i < 2; ++i) {
            if (ownRow[i]) {
                const size_t g = (size_t)gyv[i] * DIMg + gx0;
                *(f32x4*)&Pd[g] = prevq[i];   // u(t0+3)
                *(f32x4*)&Cd[g] = valq[i];    // u(t0+4)
            }
        }
    }
}

extern "C" void kernel_launch(void* const* d_in, const int* in_sizes, int n_in,
                              void* d_out, int out_size, void* d_ws, size_t ws_size,
                              hipStream_t stream) {
    const float* vel = (const float*)d_in[0];
    const float* w   = (const float*)d_in[1];
    const int*   sx  = (const int*)d_in[2];
    const int*   sy  = (const int*)d_in[3];
    const int*   ry  = (const int*)d_in[4];
    float* out = (float*)d_out;

    float* ws     = (float*)d_ws;     // needs ~5.41 MB
    float* scale  = ws;
    float* params = ws + DIMg * DIMg;
    float* fld    = params + 512;
    float* P[2]   = { fld,               fld + 2 * DIMg * DIMg };
    float* C[2]   = { fld + DIMg * DIMg, fld + 3 * DIMg * DIMg };

    time2d_init<<<(DIMg * DIMg + 255) / 256, 256, 0, stream>>>(
        vel, w, sx, sy, ry, scale, fld, params);

    dim3 grid(16, 32);   // 512 blocks, own 32x16 each
    for (int c = 0; c < NCHUNK; ++c) {
        const int s = c & 1, d = s ^ 1;
        time2d_chunk<KSTEP><<<grid, 320, 0, stream>>>(P[s], C[s], P[d], C[d],
                                                      scale, params, out,
                                                      c * KSTEP);
    }
}